// Round 10
// baseline (770.974 us; speedup 1.0000x reference)
//
#include <hip/hip_runtime.h>

#define NN 50000
#define NE 800000
#define EP (NE + NN)      // edges + self loops (= 850000)
#define HID 128
#define FIN 64
#define NG 64
#define SLOPE 0.2f

typedef unsigned short ushort_t;
typedef unsigned int uint_t;

__device__ __forceinline__ float wred_sum(float v) {
  for (int off = 32; off; off >>= 1) v += __shfl_xor(v, off);
  return v;
}
__device__ __forceinline__ ushort_t f2bf(float f) {   // RNE fp32 -> bf16
  uint_t b = __float_as_uint(f);
  b += 0x7fffu + ((b >> 16) & 1u);
  return (ushort_t)(b >> 16);
}

// ---- mean of edge weights -------------------------------------------------
__global__ void k_mean(const float* __restrict__ ew, float* __restrict__ meansum) {
  int tid = blockIdx.x * blockDim.x + threadIdx.x;
  int stride = gridDim.x * blockDim.x;
  float s = 0.f;
  for (int i = tid; i < NE; i += stride) s += ew[i];
  s = wred_sum(s);
  if ((threadIdx.x & 63) == 0) atomicAdd(meansum, s);
}

// ---- histogram of destinations (incl self loops) --------------------------
__global__ void k_hist(const int* __restrict__ edst, int* __restrict__ counts) {
  int tid = blockIdx.x * blockDim.x + threadIdx.x;
  int stride = gridDim.x * blockDim.x;
  for (int i = tid; i < EP; i += stride) {
    int d = (i < NE) ? edst[i] : (i - NE);
    atomicAdd(&counts[d], 1);
  }
}

// ---- single-block exclusive scan; also zeroes counts (reused as cursor) ---
__global__ void k_scan(int* __restrict__ counts, int* __restrict__ starts) {
  __shared__ int wsum[16];
  __shared__ int woff[16];
  int t = threadIdx.x;
  int lane = t & 63;
  int w = t >> 6;
  int carry = 0;
  for (int base = 0; base < NN; base += 1024) {
    int i = base + t;
    int v = (i < NN) ? counts[i] : 0;
    if (i < NN) counts[i] = 0;   // reset cursor for scatter
    int sc = v;
    #pragma unroll
    for (int d = 1; d < 64; d <<= 1) {
      int u = __shfl_up(sc, d);
      if (lane >= d) sc += u;
    }
    if (lane == 63) wsum[w] = sc;
    __syncthreads();
    if (w == 0 && lane < 16) {
      int x = wsum[lane];
      #pragma unroll
      for (int d = 1; d < 16; d <<= 1) {
        int u = __shfl_up(x, d);
        if (lane >= d) x += u;
      }
      woff[lane] = x;   // inclusive scan of wave sums
    }
    __syncthreads();
    int waveoff = (w == 0) ? 0 : woff[w - 1];
    if (i < NN) starts[i] = carry + waveoff + sc - v;
    carry += woff[15];
    __syncthreads();   // protect wsum/woff before next chunk
  }
  if (t == 0) starts[NN] = carry;
}

// ---- scatter edges into dst-sorted order (packed src+weight) ---------------
__global__ void k_scatter(const int* __restrict__ esrc, const int* __restrict__ edst,
                          const float* __restrict__ ew, const float* __restrict__ meansum,
                          const int* __restrict__ starts, int* __restrict__ cursor,
                          int2* __restrict__ emeta) {
  float mw = meansum[0] * (1.0f / NE);
  int tid = blockIdx.x * blockDim.x + threadIdx.x;
  int stride = gridDim.x * blockDim.x;
  for (int i = tid; i < EP; i += stride) {
    int s, d; float wv;
    if (i < NE) { s = esrc[i]; d = edst[i]; wv = ew[i]; }
    else        { s = d = i - NE; wv = mw; }
    int pos = starts[d] + atomicAdd(&cursor[d], 1);
    emeta[pos] = make_int2(s, __float_as_int(wv));
  }
}

// ---- fp32 GEMM: C[n x 128] = A[n x K] @ W[K x 128] + b ---------------------
// BF16OUT: epilogue converts to bf16 (RNE) and stores ushort4 (8B).
template <int K, int BF16OUT>
__global__ __launch_bounds__(256) void k_gemm(const float* __restrict__ A,
                                              const float* __restrict__ W,
                                              const float* __restrict__ b,
                                              void* __restrict__ Cv, int n) {
  __shared__ float As[64][K];
  int t = threadIdx.x;
  int nb = blockIdx.x * 64;
  constexpr int F4 = 16 * K;     // float4 count in the A tile
  for (int i = t; i < F4; i += 256) {
    int row = i / (K / 4);
    int c = (i % (K / 4)) * 4;
    int gn = nb + row;
    float4 v = make_float4(0.f, 0.f, 0.f, 0.f);
    if (gn < n) v = *(const float4*)(A + (size_t)gn * K + c);
    *(float4*)&As[row][c] = v;
  }
  __syncthreads();
  int fx = (t & 31) * 4;
  int ny = (t >> 5) * 8;
  float acc[8][4] = {};
  for (int k = 0; k < K; ++k) {
    float4 wv = *(const float4*)(W + (size_t)k * HID + fx);
    #pragma unroll
    for (int j = 0; j < 8; ++j) {
      float a = As[ny + j][k];
      acc[j][0] += a * wv.x; acc[j][1] += a * wv.y;
      acc[j][2] += a * wv.z; acc[j][3] += a * wv.w;
    }
  }
  float4 bb = *(const float4*)(b + fx);
  #pragma unroll
  for (int j = 0; j < 8; ++j) {
    int gn = nb + ny + j;
    if (gn < n) {
      float o0 = acc[j][0] + bb.x, o1 = acc[j][1] + bb.y;
      float o2 = acc[j][2] + bb.z, o3 = acc[j][3] + bb.w;
      if (BF16OUT) {
        ushort4 u4;
        u4.x = f2bf(o0); u4.y = f2bf(o1); u4.z = f2bf(o2); u4.w = f2bf(o3);
        *(ushort4*)((ushort_t*)Cv + (size_t)gn * HID + fx) = u4;
      } else {
        *(float4*)((float*)Cv + (size_t)gn * HID + fx) = make_float4(o0, o1, o2, o3);
      }
    }
  }
}

// ---- fully fused GATv2 edge phase (node per wave, half-wave float4) ---------
// Gathered rows kept PACKED bf16 (uint2, 16 VGPR for 8 edges) and unpacked on
// the fly in both phases -> VGPR under the 64 cliff. Edge metadata loaded
// DIRECTLY per-k (uniform address within a half -> broadcast transaction, no
// ds_bpermute). Fold-reduced logits, no-max softmax, one store per node.
__global__ __launch_bounds__(256, 8) void k_fused(const ushort_t* __restrict__ xl16,
                                                  const float* __restrict__ xr,
                                                  const int2* __restrict__ emeta,
                                                  const int* __restrict__ starts,
                                                  const float* __restrict__ We,
                                                  const float* __restrict__ att,
                                                  const float* __restrict__ bias,
                                                  float* __restrict__ hout) {
  int node = blockIdx.x * (blockDim.x >> 6) + (threadIdx.x >> 6);
  int lane = threadIdx.x & 63;
  if (node >= NN) return;
  int hl = lane & 31;
  int half = lane >> 5;
  int s0 = starts[node], s1 = starts[node + 1];
  int f = hl * 4;
  float4 xro = *(const float4*)(xr + (size_t)node * HID + f);
  float4 we  = *(const float4*)(We + f);
  float4 at  = *(const float4*)(att + f);

  int emy = 8 * half + ((hl >> 2) & 7);   // edge whose folded logit lands here
  bool b4 = (hl & 16) != 0;
  bool b3 = (hl & 8) != 0;
  bool b2 = (hl & 4) != 0;

  float ssum = 0.f;
  float4 acc = make_float4(0.f, 0.f, 0.f, 0.f);

  for (int i0 = s0; i0 < s1; i0 += 16) {
    int base = i0 + 8 * half;
    uint2 g[8];
    float wv[8];
    #pragma unroll
    for (int k = 0; k < 8; ++k) {
      int idx = min(base + k, s1 - 1);
      int2 em = emeta[idx];              // uniform within half -> broadcast
      wv[k] = __int_as_float(em.y);
      g[k] = *(const uint2*)(xl16 + (size_t)em.x * HID + f);
    }
    float p[8];
    #pragma unroll
    for (int k = 0; k < 8; ++k) {
      float v0 = __uint_as_float(g[k].x << 16);
      float v1 = __uint_as_float(g[k].x & 0xffff0000u);
      float v2 = __uint_as_float(g[k].y << 16);
      float v3 = __uint_as_float(g[k].y & 0xffff0000u);
      float t0 = v0 + xro.x + wv[k] * we.x;
      float t1 = v1 + xro.y + wv[k] * we.y;
      float t2 = v2 + xro.z + wv[k] * we.z;
      float t3 = v3 + xro.w + wv[k] * we.w;
      t0 = t0 > 0.f ? t0 : SLOPE * t0;
      t1 = t1 > 0.f ? t1 : SLOPE * t1;
      t2 = t2 > 0.f ? t2 : SLOPE * t2;
      t3 = t3 > 0.f ? t3 : SLOPE * t3;
      p[k] = t0 * at.x + t1 * at.y + t2 * at.z + t3 * at.w;
    }
    // fold-reduce: 32-lane sums of 8 logits in 9 shfls
    float sdv, rcv;
    float q0, q1, q2, q3;
    sdv = b4 ? p[0] : p[4]; rcv = __shfl_xor(sdv, 16, 32); q0 = (b4 ? p[4] : p[0]) + rcv;
    sdv = b4 ? p[1] : p[5]; rcv = __shfl_xor(sdv, 16, 32); q1 = (b4 ? p[5] : p[1]) + rcv;
    sdv = b4 ? p[2] : p[6]; rcv = __shfl_xor(sdv, 16, 32); q2 = (b4 ? p[6] : p[2]) + rcv;
    sdv = b4 ? p[3] : p[7]; rcv = __shfl_xor(sdv, 16, 32); q3 = (b4 ? p[7] : p[3]) + rcv;
    float r0, r1;
    sdv = b3 ? q0 : q2; rcv = __shfl_xor(sdv, 8, 32); r0 = (b3 ? q2 : q0) + rcv;
    sdv = b3 ? q1 : q3; rcv = __shfl_xor(sdv, 8, 32); r1 = (b3 ? q3 : q1) + rcv;
    sdv = b2 ? r0 : r1; rcv = __shfl_xor(sdv, 4, 32);
    float lg = (b2 ? r1 : r0) + rcv;
    lg += __shfl_xor(lg, 1, 32);
    lg += __shfl_xor(lg, 2, 32);
    // lg = full logit of edge (i0 + emy), replicated on 4 lanes
    float w = (i0 + emy < s1) ? __expf(lg) : 0.f;
    ssum += w;
    #pragma unroll
    for (int k = 0; k < 8; ++k) {
      float wk = __shfl(w, k << 2, 32);
      acc.x += wk * __uint_as_float(g[k].x << 16);
      acc.y += wk * __uint_as_float(g[k].x & 0xffff0000u);
      acc.z += wk * __uint_as_float(g[k].y << 16);
      acc.w += wk * __uint_as_float(g[k].y & 0xffff0000u);
    }
  }
  // merge halves (features duplicated across halves, edges disjoint)
  acc.x += __shfl_xor(acc.x, 32);
  acc.y += __shfl_xor(acc.y, 32);
  acc.z += __shfl_xor(acc.z, 32);
  acc.w += __shfl_xor(acc.w, 32);
  float st = wred_sum(ssum) * 0.25f;   // each edge's w counted on 4 lanes
  float inv = 1.0f / st;
  if (half == 0) {
    float4 bb = *(const float4*)(bias + f);
    float4 o;
    o.x = fmaxf(acc.x * inv + bb.x, 0.f);
    o.y = fmaxf(acc.y * inv + bb.y, 0.f);
    o.z = fmaxf(acc.z * inv + bb.z, 0.f);
    o.w = fmaxf(acc.w * inv + bb.w, 0.f);
    *(float4*)(hout + (size_t)node * HID + f) = o;
  }
}

// ---- graph boundaries from sorted batch ------------------------------------
__global__ void k_bounds(const int* __restrict__ batch, int* __restrict__ gs) {
  int i = blockIdx.x * blockDim.x + threadIdx.x;
  if (i >= NN) return;
  int b = batch[i];
  if (i == 0) {
    for (int g = 0; g <= b; ++g) gs[g] = 0;
  }
  int bn = (i + 1 < NN) ? batch[i + 1] : NG;
  for (int g = b + 1; g <= bn; ++g) gs[g] = i + 1;
}

// ---- segmented mean pool + final linear (one block per graph) --------------
__global__ __launch_bounds__(256) void k_pool(const float* __restrict__ h,
                                              const int* __restrict__ gs,
                                              const float* __restrict__ Wlin,
                                              const float* __restrict__ blin,
                                              float* __restrict__ out) {
  __shared__ float red[256];
  int g = blockIdx.x;
  int t = threadIdx.x;
  int f = t & 127;
  int half = t >> 7;           // 0 or 1
  int n0 = gs[g], n1 = gs[g + 1];
  float s0 = 0.f, s1 = 0.f, s2 = 0.f, s3 = 0.f;
  int n = n0 + half;
  for (; n + 6 < n1; n += 8) {
    s0 += h[(size_t)n * HID + f];
    s1 += h[(size_t)(n + 2) * HID + f];
    s2 += h[(size_t)(n + 4) * HID + f];
    s3 += h[(size_t)(n + 6) * HID + f];
  }
  for (; n < n1; n += 2) s0 += h[(size_t)n * HID + f];
  red[t] = (s0 + s1) + (s2 + s3);
  __syncthreads();
  if (t < 128) {
    float pooled = red[t] + red[t + 128];
    float cnt = (float)max(n1 - n0, 1);
    red[t] = (pooled / cnt) * Wlin[f];
  }
  __syncthreads();
  if (t < 64) {
    float v = red[t] + red[t + 64];
    v = wred_sum(v);
    if (t == 0) out[g] = v + blin[0];
  }
}

extern "C" void kernel_launch(void* const* d_in, const int* in_sizes, int n_in,
                              void* d_out, int out_size, void* d_ws, size_t ws_size,
                              hipStream_t stream) {
  const float* x     = (const float*)d_in[0];
  const int*   ei    = (const int*)d_in[1];      // [2][NE]
  const float* ew    = (const float*)d_in[2];
  const int*   batch = (const int*)d_in[3];
  const float* W1l = (const float*)d_in[4];
  const float* b1l = (const float*)d_in[5];
  const float* W1r = (const float*)d_in[6];
  const float* b1r = (const float*)d_in[7];
  const float* We1 = (const float*)d_in[8];
  const float* at1 = (const float*)d_in[9];
  const float* bi1 = (const float*)d_in[10];
  const float* W2l = (const float*)d_in[11];
  const float* b2l = (const float*)d_in[12];
  const float* W2r = (const float*)d_in[13];
  const float* b2r = (const float*)d_in[14];
  const float* We2 = (const float*)d_in[15];
  const float* at2 = (const float*)d_in[16];
  const float* bi2 = (const float*)d_in[17];
  const float* Wlin = (const float*)d_in[18];
  const float* blin = (const float*)d_in[19];

  float* ws = (float*)d_ws;
  size_t o = 0;
  float*    xr    = ws + o; o += (size_t)NN * HID;
  float*    hb    = ws + o; o += (size_t)NN * HID;
  ushort_t* xl16  = (ushort_t*)(ws + o); o += (size_t)NN * HID / 2;
  int2*     emeta = (int2*)(ws + o); o += (size_t)2 * EP;
  int*      starts = (int*)(ws + o); o += NN + 1;
  int*      gs     = (int*)(ws + o); o += NG + 1;
  size_t zoff = o;
  int*      counts  = (int*)(ws + o); o += NN;
  float*    meansum = ws + o; o += 1;
  size_t zero_bytes = (o - zoff) * sizeof(float);

  hipMemsetAsync(counts, 0, zero_bytes, stream);

  // build dst-sorted CSR (shared by both layers) + graph bounds
  k_mean<<<256, 256, 0, stream>>>(ew, meansum);
  k_hist<<<1024, 256, 0, stream>>>(ei + NE, counts);
  k_scan<<<1, 1024, 0, stream>>>(counts, starts);
  k_scatter<<<1024, 256, 0, stream>>>(ei, ei + NE, ew, meansum, starts, counts,
                                      emeta);
  k_bounds<<<(NN + 255) / 256, 256, 0, stream>>>(batch, gs);

  int gb  = (NN + 63) / 64;                       // gemm blocks
  int nbn = (NN + 3) / 4;                         // node-per-wave blocks

  // layer 1
  k_gemm<FIN, 1><<<gb, 256, 0, stream>>>(x, W1l, b1l, xl16, NN);
  k_gemm<FIN, 0><<<gb, 256, 0, stream>>>(x, W1r, b1r, xr, NN);
  k_fused<<<nbn, 256, 0, stream>>>(xl16, xr, emeta, starts, We1, at1, bi1, hb);
  // layer 2
  k_gemm<HID, 1><<<gb, 256, 0, stream>>>(hb, W2l, b2l, xl16, NN);
  k_gemm<HID, 0><<<gb, 256, 0, stream>>>(hb, W2r, b2r, xr, NN);
  k_fused<<<nbn, 256, 0, stream>>>(xl16, xr, emeta, starts, We2, at2, bi2, hb);
  // pool + head (no atomics: batch is sorted -> contiguous graph ranges)
  k_pool<<<NG, 256, 0, stream>>>(hb, gs, Wlin, blin, (float*)d_out);
}

// Round 11
// 444.869 us; speedup vs baseline: 1.7330x; 1.7330x over previous
//
#include <hip/hip_runtime.h>

#define NN 50000
#define NE 800000
#define EP (NE + NN)      // edges + self loops (= 850000)
#define HID 128
#define FIN 64
#define NG 64
#define SLOPE 0.2f

typedef unsigned short ushort_t;
typedef unsigned int uint_t;

__device__ __forceinline__ float wred_sum(float v) {
  for (int off = 32; off; off >>= 1) v += __shfl_xor(v, off);
  return v;
}
__device__ __forceinline__ ushort_t f2bf(float f) {   // RNE fp32 -> bf16
  uint_t b = __float_as_uint(f);
  b += 0x7fffu + ((b >> 16) & 1u);
  return (ushort_t)(b >> 16);
}

// ---- mean of edge weights -------------------------------------------------
__global__ void k_mean(const float* __restrict__ ew, float* __restrict__ meansum) {
  int tid = blockIdx.x * blockDim.x + threadIdx.x;
  int stride = gridDim.x * blockDim.x;
  float s = 0.f;
  for (int i = tid; i < NE; i += stride) s += ew[i];
  s = wred_sum(s);
  if ((threadIdx.x & 63) == 0) atomicAdd(meansum, s);
}

// ---- histogram of destinations (incl self loops) --------------------------
__global__ void k_hist(const int* __restrict__ edst, int* __restrict__ counts) {
  int tid = blockIdx.x * blockDim.x + threadIdx.x;
  int stride = gridDim.x * blockDim.x;
  for (int i = tid; i < EP; i += stride) {
    int d = (i < NE) ? edst[i] : (i - NE);
    atomicAdd(&counts[d], 1);
  }
}

// ---- single-block exclusive scan; also zeroes counts (reused as cursor) ---
__global__ void k_scan(int* __restrict__ counts, int* __restrict__ starts) {
  __shared__ int wsum[16];
  __shared__ int woff[16];
  int t = threadIdx.x;
  int lane = t & 63;
  int w = t >> 6;
  int carry = 0;
  for (int base = 0; base < NN; base += 1024) {
    int i = base + t;
    int v = (i < NN) ? counts[i] : 0;
    if (i < NN) counts[i] = 0;   // reset cursor for scatter
    int sc = v;
    #pragma unroll
    for (int d = 1; d < 64; d <<= 1) {
      int u = __shfl_up(sc, d);
      if (lane >= d) sc += u;
    }
    if (lane == 63) wsum[w] = sc;
    __syncthreads();
    if (w == 0 && lane < 16) {
      int x = wsum[lane];
      #pragma unroll
      for (int d = 1; d < 16; d <<= 1) {
        int u = __shfl_up(x, d);
        if (lane >= d) x += u;
      }
      woff[lane] = x;   // inclusive scan of wave sums
    }
    __syncthreads();
    int waveoff = (w == 0) ? 0 : woff[w - 1];
    if (i < NN) starts[i] = carry + waveoff + sc - v;
    carry += woff[15];
    __syncthreads();   // protect wsum/woff before next chunk
  }
  if (t == 0) starts[NN] = carry;
}

// ---- scatter edges into dst-sorted order (packed src+weight) ---------------
__global__ void k_scatter(const int* __restrict__ esrc, const int* __restrict__ edst,
                          const float* __restrict__ ew, const float* __restrict__ meansum,
                          const int* __restrict__ starts, int* __restrict__ cursor,
                          int2* __restrict__ emeta) {
  float mw = meansum[0] * (1.0f / NE);
  int tid = blockIdx.x * blockDim.x + threadIdx.x;
  int stride = gridDim.x * blockDim.x;
  for (int i = tid; i < EP; i += stride) {
    int s, d; float wv;
    if (i < NE) { s = esrc[i]; d = edst[i]; wv = ew[i]; }
    else        { s = d = i - NE; wv = mw; }
    int pos = starts[d] + atomicAdd(&cursor[d], 1);
    emeta[pos] = make_int2(s, __float_as_int(wv));
  }
}

// ---- fp32 GEMM: C[n x 128] = A[n x K] @ W[K x 128] + b ---------------------
// BF16OUT: epilogue converts to bf16 (RNE) and stores ushort4 (8B).
template <int K, int BF16OUT>
__global__ __launch_bounds__(256) void k_gemm(const float* __restrict__ A,
                                              const float* __restrict__ W,
                                              const float* __restrict__ b,
                                              void* __restrict__ Cv, int n) {
  __shared__ float As[64][K];
  int t = threadIdx.x;
  int nb = blockIdx.x * 64;
  constexpr int F4 = 16 * K;     // float4 count in the A tile
  for (int i = t; i < F4; i += 256) {
    int row = i / (K / 4);
    int c = (i % (K / 4)) * 4;
    int gn = nb + row;
    float4 v = make_float4(0.f, 0.f, 0.f, 0.f);
    if (gn < n) v = *(const float4*)(A + (size_t)gn * K + c);
    *(float4*)&As[row][c] = v;
  }
  __syncthreads();
  int fx = (t & 31) * 4;
  int ny = (t >> 5) * 8;
  float acc[8][4] = {};
  for (int k = 0; k < K; ++k) {
    float4 wv = *(const float4*)(W + (size_t)k * HID + fx);
    #pragma unroll
    for (int j = 0; j < 8; ++j) {
      float a = As[ny + j][k];
      acc[j][0] += a * wv.x; acc[j][1] += a * wv.y;
      acc[j][2] += a * wv.z; acc[j][3] += a * wv.w;
    }
  }
  float4 bb = *(const float4*)(b + fx);
  #pragma unroll
  for (int j = 0; j < 8; ++j) {
    int gn = nb + ny + j;
    if (gn < n) {
      float o0 = acc[j][0] + bb.x, o1 = acc[j][1] + bb.y;
      float o2 = acc[j][2] + bb.z, o3 = acc[j][3] + bb.w;
      if (BF16OUT) {
        ushort4 u4;
        u4.x = f2bf(o0); u4.y = f2bf(o1); u4.z = f2bf(o2); u4.w = f2bf(o3);
        *(ushort4*)((ushort_t*)Cv + (size_t)gn * HID + fx) = u4;
      } else {
        *(float4*)((float*)Cv + (size_t)gn * HID + fx) = make_float4(o0, o1, o2, o3);
      }
    }
  }
}

// ---- fully fused GATv2 edge phase (node per wave, half-wave float4) ---------
// Gathered rows kept PACKED bf16 (uint2); edge weight stashed in p[] until
// consumed (no separate wv[] -> -8 VGPR). Direct broadcast metadata loads.
// launch_bounds(256,4): cap combined VGPR+AGPR at 128 (no spill, no AGPR
// bloat past 128 which halves occupancy). Fold-reduced logits, no-max
// softmax, one store per node.
__global__ __launch_bounds__(256, 4) void k_fused(const ushort_t* __restrict__ xl16,
                                                  const float* __restrict__ xr,
                                                  const int2* __restrict__ emeta,
                                                  const int* __restrict__ starts,
                                                  const float* __restrict__ We,
                                                  const float* __restrict__ att,
                                                  const float* __restrict__ bias,
                                                  float* __restrict__ hout) {
  int node = blockIdx.x * (blockDim.x >> 6) + (threadIdx.x >> 6);
  int lane = threadIdx.x & 63;
  if (node >= NN) return;
  int hl = lane & 31;
  int half = lane >> 5;
  int s0 = starts[node], s1 = starts[node + 1];
  int f = hl * 4;
  float4 xro = *(const float4*)(xr + (size_t)node * HID + f);
  float4 we  = *(const float4*)(We + f);
  float4 at  = *(const float4*)(att + f);

  int emy = 8 * half + ((hl >> 2) & 7);   // edge whose folded logit lands here
  bool b4 = (hl & 16) != 0;
  bool b3 = (hl & 8) != 0;
  bool b2 = (hl & 4) != 0;

  float ssum = 0.f;
  float4 acc = make_float4(0.f, 0.f, 0.f, 0.f);

  for (int i0 = s0; i0 < s1; i0 += 16) {
    int base = i0 + 8 * half;
    uint2 g[8];
    float p[8];                          // holds edge weight, then logit
    #pragma unroll
    for (int k = 0; k < 8; ++k) {
      int idx = min(base + k, s1 - 1);
      int2 em = emeta[idx];              // uniform within half -> broadcast
      p[k] = __int_as_float(em.y);
      g[k] = *(const uint2*)(xl16 + (size_t)em.x * HID + f);
    }
    #pragma unroll
    for (int k = 0; k < 8; ++k) {
      float wk = p[k];
      float t0 = __uint_as_float(g[k].x << 16)          + xro.x + wk * we.x;
      float t1 = __uint_as_float(g[k].x & 0xffff0000u)  + xro.y + wk * we.y;
      float t2 = __uint_as_float(g[k].y << 16)          + xro.z + wk * we.z;
      float t3 = __uint_as_float(g[k].y & 0xffff0000u)  + xro.w + wk * we.w;
      t0 = t0 > 0.f ? t0 : SLOPE * t0;
      t1 = t1 > 0.f ? t1 : SLOPE * t1;
      t2 = t2 > 0.f ? t2 : SLOPE * t2;
      t3 = t3 > 0.f ? t3 : SLOPE * t3;
      p[k] = t0 * at.x + t1 * at.y + t2 * at.z + t3 * at.w;
    }
    // fold-reduce: 32-lane sums of 8 logits in 9 shfls
    float sdv, rcv;
    float q0, q1, q2, q3;
    sdv = b4 ? p[0] : p[4]; rcv = __shfl_xor(sdv, 16, 32); q0 = (b4 ? p[4] : p[0]) + rcv;
    sdv = b4 ? p[1] : p[5]; rcv = __shfl_xor(sdv, 16, 32); q1 = (b4 ? p[5] : p[1]) + rcv;
    sdv = b4 ? p[2] : p[6]; rcv = __shfl_xor(sdv, 16, 32); q2 = (b4 ? p[6] : p[2]) + rcv;
    sdv = b4 ? p[3] : p[7]; rcv = __shfl_xor(sdv, 16, 32); q3 = (b4 ? p[7] : p[3]) + rcv;
    float r0, r1;
    sdv = b3 ? q0 : q2; rcv = __shfl_xor(sdv, 8, 32); r0 = (b3 ? q2 : q0) + rcv;
    sdv = b3 ? q1 : q3; rcv = __shfl_xor(sdv, 8, 32); r1 = (b3 ? q3 : q1) + rcv;
    sdv = b2 ? r0 : r1; rcv = __shfl_xor(sdv, 4, 32);
    float lg = (b2 ? r1 : r0) + rcv;
    lg += __shfl_xor(lg, 1, 32);
    lg += __shfl_xor(lg, 2, 32);
    // lg = full logit of edge (i0 + emy), replicated on 4 lanes
    float w = (i0 + emy < s1) ? __expf(lg) : 0.f;
    ssum += w;
    #pragma unroll
    for (int k = 0; k < 8; ++k) {
      float wk = __shfl(w, k << 2, 32);
      acc.x += wk * __uint_as_float(g[k].x << 16);
      acc.y += wk * __uint_as_float(g[k].x & 0xffff0000u);
      acc.z += wk * __uint_as_float(g[k].y << 16);
      acc.w += wk * __uint_as_float(g[k].y & 0xffff0000u);
    }
  }
  // merge halves (features duplicated across halves, edges disjoint)
  acc.x += __shfl_xor(acc.x, 32);
  acc.y += __shfl_xor(acc.y, 32);
  acc.z += __shfl_xor(acc.z, 32);
  acc.w += __shfl_xor(acc.w, 32);
  float st = wred_sum(ssum) * 0.25f;   // each edge's w counted on 4 lanes
  float inv = 1.0f / st;
  if (half == 0) {
    float4 bb = *(const float4*)(bias + f);
    float4 o;
    o.x = fmaxf(acc.x * inv + bb.x, 0.f);
    o.y = fmaxf(acc.y * inv + bb.y, 0.f);
    o.z = fmaxf(acc.z * inv + bb.z, 0.f);
    o.w = fmaxf(acc.w * inv + bb.w, 0.f);
    *(float4*)(hout + (size_t)node * HID + f) = o;
  }
}

// ---- graph boundaries from sorted batch ------------------------------------
__global__ void k_bounds(const int* __restrict__ batch, int* __restrict__ gs) {
  int i = blockIdx.x * blockDim.x + threadIdx.x;
  if (i >= NN) return;
  int b = batch[i];
  if (i == 0) {
    for (int g = 0; g <= b; ++g) gs[g] = 0;
  }
  int bn = (i + 1 < NN) ? batch[i + 1] : NG;
  for (int g = b + 1; g <= bn; ++g) gs[g] = i + 1;
}

// ---- segmented mean pool + final linear (one block per graph) --------------
__global__ __launch_bounds__(256) void k_pool(const float* __restrict__ h,
                                              const int* __restrict__ gs,
                                              const float* __restrict__ Wlin,
                                              const float* __restrict__ blin,
                                              float* __restrict__ out) {
  __shared__ float red[256];
  int g = blockIdx.x;
  int t = threadIdx.x;
  int f = t & 127;
  int half = t >> 7;           // 0 or 1
  int n0 = gs[g], n1 = gs[g + 1];
  float s0 = 0.f, s1 = 0.f, s2 = 0.f, s3 = 0.f;
  int n = n0 + half;
  for (; n + 6 < n1; n += 8) {
    s0 += h[(size_t)n * HID + f];
    s1 += h[(size_t)(n + 2) * HID + f];
    s2 += h[(size_t)(n + 4) * HID + f];
    s3 += h[(size_t)(n + 6) * HID + f];
  }
  for (; n < n1; n += 2) s0 += h[(size_t)n * HID + f];
  red[t] = (s0 + s1) + (s2 + s3);
  __syncthreads();
  if (t < 128) {
    float pooled = red[t] + red[t + 128];
    float cnt = (float)max(n1 - n0, 1);
    red[t] = (pooled / cnt) * Wlin[f];
  }
  __syncthreads();
  if (t < 64) {
    float v = red[t] + red[t + 64];
    v = wred_sum(v);
    if (t == 0) out[g] = v + blin[0];
  }
}

extern "C" void kernel_launch(void* const* d_in, const int* in_sizes, int n_in,
                              void* d_out, int out_size, void* d_ws, size_t ws_size,
                              hipStream_t stream) {
  const float* x     = (const float*)d_in[0];
  const int*   ei    = (const int*)d_in[1];      // [2][NE]
  const float* ew    = (const float*)d_in[2];
  const int*   batch = (const int*)d_in[3];
  const float* W1l = (const float*)d_in[4];
  const float* b1l = (const float*)d_in[5];
  const float* W1r = (const float*)d_in[6];
  const float* b1r = (const float*)d_in[7];
  const float* We1 = (const float*)d_in[8];
  const float* at1 = (const float*)d_in[9];
  const float* bi1 = (const float*)d_in[10];
  const float* W2l = (const float*)d_in[11];
  const float* b2l = (const float*)d_in[12];
  const float* W2r = (const float*)d_in[13];
  const float* b2r = (const float*)d_in[14];
  const float* We2 = (const float*)d_in[15];
  const float* at2 = (const float*)d_in[16];
  const float* bi2 = (const float*)d_in[17];
  const float* Wlin = (const float*)d_in[18];
  const float* blin = (const float*)d_in[19];

  float* ws = (float*)d_ws;
  size_t o = 0;
  float*    xr    = ws + o; o += (size_t)NN * HID;
  float*    hb    = ws + o; o += (size_t)NN * HID;
  ushort_t* xl16  = (ushort_t*)(ws + o); o += (size_t)NN * HID / 2;
  int2*     emeta = (int2*)(ws + o); o += (size_t)2 * EP;
  int*      starts = (int*)(ws + o); o += NN + 1;
  int*      gs     = (int*)(ws + o); o += NG + 1;
  size_t zoff = o;
  int*      counts  = (int*)(ws + o); o += NN;
  float*    meansum = ws + o; o += 1;
  size_t zero_bytes = (o - zoff) * sizeof(float);

  hipMemsetAsync(counts, 0, zero_bytes, stream);

  // build dst-sorted CSR (shared by both layers) + graph bounds
  k_mean<<<256, 256, 0, stream>>>(ew, meansum);
  k_hist<<<1024, 256, 0, stream>>>(ei + NE, counts);
  k_scan<<<1, 1024, 0, stream>>>(counts, starts);
  k_scatter<<<1024, 256, 0, stream>>>(ei, ei + NE, ew, meansum, starts, counts,
                                      emeta);
  k_bounds<<<(NN + 255) / 256, 256, 0, stream>>>(batch, gs);

  int gb  = (NN + 63) / 64;                       // gemm blocks
  int nbn = (NN + 3) / 4;                         // node-per-wave blocks

  // layer 1
  k_gemm<FIN, 1><<<gb, 256, 0, stream>>>(x, W1l, b1l, xl16, NN);
  k_gemm<FIN, 0><<<gb, 256, 0, stream>>>(x, W1r, b1r, xr, NN);
  k_fused<<<nbn, 256, 0, stream>>>(xl16, xr, emeta, starts, We1, at1, bi1, hb);
  // layer 2
  k_gemm<HID, 1><<<gb, 256, 0, stream>>>(hb, W2l, b2l, xl16, NN);
  k_gemm<HID, 0><<<gb, 256, 0, stream>>>(hb, W2r, b2r, xr, NN);
  k_fused<<<nbn, 256, 0, stream>>>(xl16, xr, emeta, starts, We2, at2, bi2, hb);
  // pool + head (no atomics: batch is sorted -> contiguous graph ranges)
  k_pool<<<NG, 256, 0, stream>>>(hb, gs, Wlin, blin, (float*)d_out);
}

// Round 13
// 421.808 us; speedup vs baseline: 1.8278x; 1.0547x over previous
//
#include <hip/hip_runtime.h>

#define NN 50000
#define NE 800000
#define EP (NE + NN)      // edges + self loops (= 850000)
#define HID 128
#define FIN 64
#define NG 64
#define SLOPE 0.2f

typedef unsigned short ushort_t;
typedef unsigned int uint_t;

__device__ __forceinline__ float wred_sum(float v) {
  for (int off = 32; off; off >>= 1) v += __shfl_xor(v, off);
  return v;
}
__device__ __forceinline__ ushort_t f2bf(float f) {   // RNE fp32 -> bf16
  uint_t b = __float_as_uint(f);
  b += 0x7fffu + ((b >> 16) & 1u);
  return (ushort_t)(b >> 16);
}

// NOTE: parameter names must not collide with .x/.y/.z/.w member tokens
#define FMA4(A_, S_, W_) \
  A_.x += (S_) * W_.x; A_.y += (S_) * W_.y; \
  A_.z += (S_) * W_.z; A_.w += (S_) * W_.w;

// ---- mean of edge weights -------------------------------------------------
__global__ void k_mean(const float* __restrict__ ew, float* __restrict__ meansum) {
  int tid = blockIdx.x * blockDim.x + threadIdx.x;
  int stride = gridDim.x * blockDim.x;
  float s = 0.f;
  for (int i = tid; i < NE; i += stride) s += ew[i];
  s = wred_sum(s);
  if ((threadIdx.x & 63) == 0) atomicAdd(meansum, s);
}

// ---- histogram of destinations (incl self loops) --------------------------
__global__ void k_hist(const int* __restrict__ edst, int* __restrict__ counts) {
  int tid = blockIdx.x * blockDim.x + threadIdx.x;
  int stride = gridDim.x * blockDim.x;
  for (int i = tid; i < EP; i += stride) {
    int d = (i < NE) ? edst[i] : (i - NE);
    atomicAdd(&counts[d], 1);
  }
}

// ---- single-block exclusive scan; also zeroes counts (reused as cursor) ---
__global__ void k_scan(int* __restrict__ counts, int* __restrict__ starts) {
  __shared__ int wsum[16];
  __shared__ int woff[16];
  int t = threadIdx.x;
  int lane = t & 63;
  int w = t >> 6;
  int carry = 0;
  for (int base = 0; base < NN; base += 1024) {
    int i = base + t;
    int v = (i < NN) ? counts[i] : 0;
    if (i < NN) counts[i] = 0;   // reset cursor for scatter
    int sc = v;
    #pragma unroll
    for (int d = 1; d < 64; d <<= 1) {
      int u = __shfl_up(sc, d);
      if (lane >= d) sc += u;
    }
    if (lane == 63) wsum[w] = sc;
    __syncthreads();
    if (w == 0 && lane < 16) {
      int x = wsum[lane];
      #pragma unroll
      for (int d = 1; d < 16; d <<= 1) {
        int u = __shfl_up(x, d);
        if (lane >= d) x += u;
      }
      woff[lane] = x;   // inclusive scan of wave sums
    }
    __syncthreads();
    int waveoff = (w == 0) ? 0 : woff[w - 1];
    if (i < NN) starts[i] = carry + waveoff + sc - v;
    carry += woff[15];
    __syncthreads();   // protect wsum/woff before next chunk
  }
  if (t == 0) starts[NN] = carry;
}

// ---- scatter edges into dst-sorted order (packed src+weight) ---------------
__global__ void k_scatter(const int* __restrict__ esrc, const int* __restrict__ edst,
                          const float* __restrict__ ew, const float* __restrict__ meansum,
                          const int* __restrict__ starts, int* __restrict__ cursor,
                          int2* __restrict__ emeta) {
  float mw = meansum[0] * (1.0f / NE);
  int tid = blockIdx.x * blockDim.x + threadIdx.x;
  int stride = gridDim.x * blockDim.x;
  for (int i = tid; i < EP; i += stride) {
    int s, d; float wv;
    if (i < NE) { s = esrc[i]; d = edst[i]; wv = ew[i]; }
    else        { s = d = i - NE; wv = mw; }
    int pos = starts[d] + atomicAdd(&cursor[d], 1);
    emeta[pos] = make_int2(s, __float_as_int(wv));
  }
}

// ---- dual fp32 GEMM: xl16 = bf16(A@Wl+bl), xr = A@Wr+br ---------------------
// A tile staged+LDS-read ONCE for both weight matrices; k consumed 4 at a
// time via ds_read_b128 (wave-uniform address -> broadcast, conflict-free).
template <int K>
__global__ __launch_bounds__(256) void k_gemm2(const float* __restrict__ A,
                                               const float* __restrict__ Wl,
                                               const float* __restrict__ bl,
                                               const float* __restrict__ Wr,
                                               const float* __restrict__ br,
                                               ushort_t* __restrict__ xlout,
                                               float* __restrict__ xrout, int n) {
  __shared__ float As[64][K];
  int t = threadIdx.x;
  int nb = blockIdx.x * 64;
  constexpr int F4 = 16 * K;     // float4 count in the A tile
  for (int i = t; i < F4; i += 256) {
    int row = i / (K / 4);
    int c = (i % (K / 4)) * 4;
    int gn = nb + row;
    float4 v = make_float4(0.f, 0.f, 0.f, 0.f);
    if (gn < n) v = *(const float4*)(A + (size_t)gn * K + c);
    *(float4*)&As[row][c] = v;
  }
  __syncthreads();
  int fx = (t & 31) * 4;
  int ny = (t >> 5) * 8;
  float4 accL[8], accR[8];
  #pragma unroll
  for (int j = 0; j < 8; ++j) {
    accL[j] = make_float4(0.f, 0.f, 0.f, 0.f);
    accR[j] = make_float4(0.f, 0.f, 0.f, 0.f);
  }
  for (int k4 = 0; k4 < K; k4 += 4) {
    float4 wl0 = *(const float4*)(Wl + (size_t)(k4 + 0) * HID + fx);
    float4 wl1 = *(const float4*)(Wl + (size_t)(k4 + 1) * HID + fx);
    float4 wl2 = *(const float4*)(Wl + (size_t)(k4 + 2) * HID + fx);
    float4 wl3 = *(const float4*)(Wl + (size_t)(k4 + 3) * HID + fx);
    float4 wr0 = *(const float4*)(Wr + (size_t)(k4 + 0) * HID + fx);
    float4 wr1 = *(const float4*)(Wr + (size_t)(k4 + 1) * HID + fx);
    float4 wr2 = *(const float4*)(Wr + (size_t)(k4 + 2) * HID + fx);
    float4 wr3 = *(const float4*)(Wr + (size_t)(k4 + 3) * HID + fx);
    #pragma unroll
    for (int j = 0; j < 8; ++j) {
      float4 a = *(const float4*)&As[ny + j][k4];
      FMA4(accL[j], a.x, wl0); FMA4(accL[j], a.y, wl1);
      FMA4(accL[j], a.z, wl2); FMA4(accL[j], a.w, wl3);
      FMA4(accR[j], a.x, wr0); FMA4(accR[j], a.y, wr1);
      FMA4(accR[j], a.z, wr2); FMA4(accR[j], a.w, wr3);
    }
  }
  float4 bbl = *(const float4*)(bl + fx);
  float4 bbr = *(const float4*)(br + fx);
  #pragma unroll
  for (int j = 0; j < 8; ++j) {
    int gn = nb + ny + j;
    if (gn < n) {
      ushort4 u4;
      u4.x = f2bf(accL[j].x + bbl.x); u4.y = f2bf(accL[j].y + bbl.y);
      u4.z = f2bf(accL[j].z + bbl.z); u4.w = f2bf(accL[j].w + bbl.w);
      *(ushort4*)(xlout + (size_t)gn * HID + fx) = u4;
      float4 o = make_float4(accR[j].x + bbr.x, accR[j].y + bbr.y,
                             accR[j].z + bbr.z, accR[j].w + bbr.w);
      *(float4*)(xrout + (size_t)gn * HID + fx) = o;
    }
  }
}

// ---- fully fused GATv2 edge phase (node per wave, half-wave float4) ---------
__global__ __launch_bounds__(256, 4) void k_fused(const ushort_t* __restrict__ xl16,
                                                  const float* __restrict__ xr,
                                                  const int2* __restrict__ emeta,
                                                  const int* __restrict__ starts,
                                                  const float* __restrict__ We,
                                                  const float* __restrict__ att,
                                                  const float* __restrict__ bias,
                                                  float* __restrict__ hout) {
  int node = blockIdx.x * (blockDim.x >> 6) + (threadIdx.x >> 6);
  int lane = threadIdx.x & 63;
  if (node >= NN) return;
  int hl = lane & 31;
  int half = lane >> 5;
  int s0 = starts[node], s1 = starts[node + 1];
  int f = hl * 4;
  float4 xro = *(const float4*)(xr + (size_t)node * HID + f);
  float4 we  = *(const float4*)(We + f);
  float4 at  = *(const float4*)(att + f);

  int emy = 8 * half + ((hl >> 2) & 7);   // edge whose folded logit lands here
  bool b4 = (hl & 16) != 0;
  bool b3 = (hl & 8) != 0;
  bool b2 = (hl & 4) != 0;

  float ssum = 0.f;
  float4 acc = make_float4(0.f, 0.f, 0.f, 0.f);

  for (int i0 = s0; i0 < s1; i0 += 16) {
    int base = i0 + 8 * half;
    uint2 g[8];
    float p[8];                          // holds edge weight, then logit
    #pragma unroll
    for (int k = 0; k < 8; ++k) {
      int idx = min(base + k, s1 - 1);
      int2 em = emeta[idx];              // uniform within half -> broadcast
      p[k] = __int_as_float(em.y);
      g[k] = *(const uint2*)(xl16 + (size_t)em.x * HID + f);
    }
    #pragma unroll
    for (int k = 0; k < 8; ++k) {
      float wk = p[k];
      float t0 = __uint_as_float(g[k].x << 16)          + xro.x + wk * we.x;
      float t1 = __uint_as_float(g[k].x & 0xffff0000u)  + xro.y + wk * we.y;
      float t2 = __uint_as_float(g[k].y << 16)          + xro.z + wk * we.z;
      float t3 = __uint_as_float(g[k].y & 0xffff0000u)  + xro.w + wk * we.w;
      t0 = t0 > 0.f ? t0 : SLOPE * t0;
      t1 = t1 > 0.f ? t1 : SLOPE * t1;
      t2 = t2 > 0.f ? t2 : SLOPE * t2;
      t3 = t3 > 0.f ? t3 : SLOPE * t3;
      p[k] = t0 * at.x + t1 * at.y + t2 * at.z + t3 * at.w;
    }
    // fold-reduce: 32-lane sums of 8 logits in 9 shfls
    float sdv, rcv;
    float q0, q1, q2, q3;
    sdv = b4 ? p[0] : p[4]; rcv = __shfl_xor(sdv, 16, 32); q0 = (b4 ? p[4] : p[0]) + rcv;
    sdv = b4 ? p[1] : p[5]; rcv = __shfl_xor(sdv, 16, 32); q1 = (b4 ? p[5] : p[1]) + rcv;
    sdv = b4 ? p[2] : p[6]; rcv = __shfl_xor(sdv, 16, 32); q2 = (b4 ? p[6] : p[2]) + rcv;
    sdv = b4 ? p[3] : p[7]; rcv = __shfl_xor(sdv, 16, 32); q3 = (b4 ? p[7] : p[3]) + rcv;
    float r0, r1;
    sdv = b3 ? q0 : q2; rcv = __shfl_xor(sdv, 8, 32); r0 = (b3 ? q2 : q0) + rcv;
    sdv = b3 ? q1 : q3; rcv = __shfl_xor(sdv, 8, 32); r1 = (b3 ? q3 : q1) + rcv;
    sdv = b2 ? r0 : r1; rcv = __shfl_xor(sdv, 4, 32);
    float lg = (b2 ? r1 : r0) + rcv;
    lg += __shfl_xor(lg, 1, 32);
    lg += __shfl_xor(lg, 2, 32);
    // lg = full logit of edge (i0 + emy), replicated on 4 lanes
    float w = (i0 + emy < s1) ? __expf(lg) : 0.f;
    ssum += w;
    #pragma unroll
    for (int k = 0; k < 8; ++k) {
      float wk = __shfl(w, k << 2, 32);
      acc.x += wk * __uint_as_float(g[k].x << 16);
      acc.y += wk * __uint_as_float(g[k].x & 0xffff0000u);
      acc.z += wk * __uint_as_float(g[k].y << 16);
      acc.w += wk * __uint_as_float(g[k].y & 0xffff0000u);
    }
  }
  // merge halves (features duplicated across halves, edges disjoint)
  acc.x += __shfl_xor(acc.x, 32);
  acc.y += __shfl_xor(acc.y, 32);
  acc.z += __shfl_xor(acc.z, 32);
  acc.w += __shfl_xor(acc.w, 32);
  float st = wred_sum(ssum) * 0.25f;   // each edge's w counted on 4 lanes
  float inv = 1.0f / st;
  if (half == 0) {
    float4 bb = *(const float4*)(bias + f);
    float4 o;
    o.x = fmaxf(acc.x * inv + bb.x, 0.f);
    o.y = fmaxf(acc.y * inv + bb.y, 0.f);
    o.z = fmaxf(acc.z * inv + bb.z, 0.f);
    o.w = fmaxf(acc.w * inv + bb.w, 0.f);
    *(float4*)(hout + (size_t)node * HID + f) = o;
  }
}

// ---- graph boundaries from sorted batch ------------------------------------
__global__ void k_bounds(const int* __restrict__ batch, int* __restrict__ gs) {
  int i = blockIdx.x * blockDim.x + threadIdx.x;
  if (i >= NN) return;
  int b = batch[i];
  if (i == 0) {
    for (int g = 0; g <= b; ++g) gs[g] = 0;
  }
  int bn = (i + 1 < NN) ? batch[i + 1] : NG;
  for (int g = b + 1; g <= bn; ++g) gs[g] = i + 1;
}

// ---- segmented mean pool + final linear (one block per graph) --------------
__global__ __launch_bounds__(256) void k_pool(const float* __restrict__ h,
                                              const int* __restrict__ gs,
                                              const float* __restrict__ Wlin,
                                              const float* __restrict__ blin,
                                              float* __restrict__ out) {
  __shared__ float red[256];
  int g = blockIdx.x;
  int t = threadIdx.x;
  int f = t & 127;
  int half = t >> 7;           // 0 or 1
  int n0 = gs[g], n1 = gs[g + 1];
  float s0 = 0.f, s1 = 0.f, s2 = 0.f, s3 = 0.f;
  int n = n0 + half;
  for (; n + 6 < n1; n += 8) {
    s0 += h[(size_t)n * HID + f];
    s1 += h[(size_t)(n + 2) * HID + f];
    s2 += h[(size_t)(n + 4) * HID + f];
    s3 += h[(size_t)(n + 6) * HID + f];
  }
  for (; n < n1; n += 2) s0 += h[(size_t)n * HID + f];
  red[t] = (s0 + s1) + (s2 + s3);
  __syncthreads();
  if (t < 128) {
    float pooled = red[t] + red[t + 128];
    float cnt = (float)max(n1 - n0, 1);
    red[t] = (pooled / cnt) * Wlin[f];
  }
  __syncthreads();
  if (t < 64) {
    float v = red[t] + red[t + 64];
    v = wred_sum(v);
    if (t == 0) out[g] = v + blin[0];
  }
}

extern "C" void kernel_launch(void* const* d_in, const int* in_sizes, int n_in,
                              void* d_out, int out_size, void* d_ws, size_t ws_size,
                              hipStream_t stream) {
  const float* x     = (const float*)d_in[0];
  const int*   ei    = (const int*)d_in[1];      // [2][NE]
  const float* ew    = (const float*)d_in[2];
  const int*   batch = (const int*)d_in[3];
  const float* W1l = (const float*)d_in[4];
  const float* b1l = (const float*)d_in[5];
  const float* W1r = (const float*)d_in[6];
  const float* b1r = (const float*)d_in[7];
  const float* We1 = (const float*)d_in[8];
  const float* at1 = (const float*)d_in[9];
  const float* bi1 = (const float*)d_in[10];
  const float* W2l = (const float*)d_in[11];
  const float* b2l = (const float*)d_in[12];
  const float* W2r = (const float*)d_in[13];
  const float* b2r = (const float*)d_in[14];
  const float* We2 = (const float*)d_in[15];
  const float* at2 = (const float*)d_in[16];
  const float* bi2 = (const float*)d_in[17];
  const float* Wlin = (const float*)d_in[18];
  const float* blin = (const float*)d_in[19];

  float* ws = (float*)d_ws;
  size_t o = 0;
  float*    xr    = ws + o; o += (size_t)NN * HID;
  float*    hb    = ws + o; o += (size_t)NN * HID;
  ushort_t* xl16  = (ushort_t*)(ws + o); o += (size_t)NN * HID / 2;
  int2*     emeta = (int2*)(ws + o); o += (size_t)2 * EP;
  int*      starts = (int*)(ws + o); o += NN + 1;
  int*      gs     = (int*)(ws + o); o += NG + 1;
  size_t zoff = o;
  int*      counts  = (int*)(ws + o); o += NN;
  float*    meansum = ws + o; o += 1;
  size_t zero_bytes = (o - zoff) * sizeof(float);

  hipMemsetAsync(counts, 0, zero_bytes, stream);

  // build dst-sorted CSR (shared by both layers) + graph bounds
  k_mean<<<256, 256, 0, stream>>>(ew, meansum);
  k_hist<<<1024, 256, 0, stream>>>(ei + NE, counts);
  k_scan<<<1, 1024, 0, stream>>>(counts, starts);
  k_scatter<<<1024, 256, 0, stream>>>(ei, ei + NE, ew, meansum, starts, counts,
                                      emeta);
  k_bounds<<<(NN + 255) / 256, 256, 0, stream>>>(batch, gs);

  int gb  = (NN + 63) / 64;                       // gemm blocks
  int nbn = (NN + 3) / 4;                         // node-per-wave blocks

  // layer 1 (one dual-GEMM instead of two GEMMs)
  k_gemm2<FIN><<<gb, 256, 0, stream>>>(x, W1l, b1l, W1r, b1r, xl16, xr, NN);
  k_fused<<<nbn, 256, 0, stream>>>(xl16, xr, emeta, starts, We1, at1, bi1, hb);
  // layer 2
  k_gemm2<HID><<<gb, 256, 0, stream>>>(hb, W2l, b2l, W2r, b2r, xl16, xr, NN);
  k_fused<<<nbn, 256, 0, stream>>>(xl16, xr, emeta, starts, We2, at2, bi2, hb);
  // pool + head (no atomics: batch is sorted -> contiguous graph ranges)
  k_pool<<<NG, 256, 0, stream>>>(hb, gs, Wlin, blin, (float*)d_out);
}